// Round 2
// 124.902 us; speedup vs baseline: 1.0264x; 1.0264x over previous
//
#include <hip/hip_runtime.h>

#define CONS_RATE 0.001f
#define CLAMP_V   10.0f

// e^(2s) = 2^(s * 2/ln2)
#define TWO_LOG2E 2.88539008177792681472f

#if defined(__has_builtin)
#  if __has_builtin(__builtin_amdgcn_exp2f)
#    define EXP2F(x) __builtin_amdgcn_exp2f(x)
#  endif
#endif
#ifndef EXP2F
// fallback: exp2(x) = exp(x*ln2); __expf lowers to v_mul + v_exp
#  define EXP2F(x) __expf(0.69314718055994530942f * (x))
#endif

// Native clang vector type: __builtin_nontemporal_store requires this
// (HIP's float4 is a class and is rejected).
typedef float f32x4 __attribute__((ext_vector_type(4)));

// Per-element: out = clamp(w + 0.001*tanh(b2 + sum_j w2_j * relu(a_j*w + c_j)))
// a_j = W1[0][j] (SGPR), v_j = W2[j] (SGPR),
// c_j = cs*W1[1][j] + fs*W1[2][j] + b1[j]  -> PINNED TO VGPR so every
// v_fma reads at most one SGPR (HW limit: 1 SGPR operand per VALU op),
// eliminating the per-term v_mov rematerialization the 32-VGPR build had.

__global__ __launch_bounds__(256) void ConsolidationDynamics_70068096467285_kernel(
    const float* __restrict__ w,
    const float* __restrict__ cs_p,
    const float* __restrict__ fs_p,
    const float* __restrict__ W1,   // (3,16) row-major
    const float* __restrict__ b1,   // (16,)
    const float* __restrict__ W2,   // (16,1)
    const float* __restrict__ b2,   // (1,)
    float* __restrict__ out,
    int n)
{
    const float cs = cs_p[0];
    const float fs = fs_p[0];
    float bb2 = b2[0];
    asm("" : "+v"(bb2));   // force VGPR residence

#define COEF(J) \
    const float a##J = W1[J]; \
    const float v##J = W2[J]; \
    float c##J = fmaf(cs, W1[16 + J], fmaf(fs, W1[32 + J], b1[J])); \
    asm("" : "+v"(c##J));
    COEF(0)  COEF(1)  COEF(2)  COEF(3)
    COEF(4)  COEF(5)  COEF(6)  COEF(7)
    COEF(8)  COEF(9)  COEF(10) COEF(11)
    COEF(12) COEF(13) COEF(14) COEF(15)
#undef COEF

// One term: v_fma (1 SGPR a, VGPR r, VGPR c) ; v_max (inline 0) ; v_fma (1 SGPR v)
#define TERM(J, sacc) { float h = fmaf(r_, a##J, c##J); h = fmaxf(h, 0.0f); \
                        sacc = fmaf(h, v##J, sacc); }

// Two accumulator chains halve the dependent-FMA latency per element.
#define EVAL(rr, d) { \
    const float r_ = (rr); \
    float h0 = fmaf(r_, a0, c0); h0 = fmaxf(h0, 0.0f); float s0 = fmaf(h0, v0, bb2); \
    float h1 = fmaf(r_, a1, c1); h1 = fmaxf(h1, 0.0f); float s1 = h1 * v1; \
    TERM(2, s0)  TERM(3, s1)  TERM(4, s0)  TERM(5, s1)  \
    TERM(6, s0)  TERM(7, s1)  TERM(8, s0)  TERM(9, s1)  \
    TERM(10, s0) TERM(11, s1) TERM(12, s0) TERM(13, s1) \
    TERM(14, s0) TERM(15, s1) \
    const float e  = EXP2F((s0 + s1) * TWO_LOG2E); \
    const float u  = fmaf(-2.0f, __builtin_amdgcn_rcpf(e + 1.0f), 1.0f); \
    const float nw = fmaf(u, CONS_RATE, r_); \
    (d) = fminf(fmaxf(nw, -CLAMP_V), CLAMP_V); }

    const int n4 = n >> 2;
    const f32x4* __restrict__ w4 = (const f32x4*)w;
    f32x4* __restrict__ o4 = (f32x4*)out;

    const int nthreads = gridDim.x * blockDim.x;
    const int tid      = blockIdx.x * blockDim.x + threadIdx.x;
    const int step     = nthreads * 2;

    int i0 = tid;
    int i1 = tid + nthreads;

    // Main: 2 coalesced float4 streams (8 elements) in flight per thread.
    // Register footprint ~55 VGPRs -> 8 waves/SIMD; grid of 2048 blocks fills
    // all 256 CUs in ONE scheduling round (8 blocks/CU).
    for (; i1 < n4; i0 += step, i1 += step) {
        const f32x4 A = w4[i0];
        const f32x4 B = w4[i1];
        f32x4 oA, oB;
        EVAL(A.x, oA.x) EVAL(A.y, oA.y) EVAL(A.z, oA.z) EVAL(A.w, oA.w)
        EVAL(B.x, oB.x) EVAL(B.y, oB.y) EVAL(B.z, oB.z) EVAL(B.w, oB.w)
        // nt stores: don't let the write stream evict the (re-read) input from L3
        __builtin_nontemporal_store(oA, &o4[i0]);
        __builtin_nontemporal_store(oB, &o4[i1]);
    }
    // Remainder float4s.
    for (; i0 < n4; i0 += nthreads) {
        const f32x4 A = w4[i0];
        f32x4 oA;
        EVAL(A.x, oA.x) EVAL(A.y, oA.y) EVAL(A.z, oA.z) EVAL(A.w, oA.w)
        __builtin_nontemporal_store(oA, &o4[i0]);
    }
    // Scalar tail (n % 4).
    for (int i = (n4 << 2) + tid; i < n; i += nthreads) {
        const float r = w[i];
        float d;
        EVAL(r, d)
        out[i] = d;
    }
#undef EVAL
#undef TERM
}

extern "C" void kernel_launch(void* const* d_in, const int* in_sizes, int n_in,
                              void* d_out, int out_size, void* d_ws, size_t ws_size,
                              hipStream_t stream) {
    const float* w   = (const float*)d_in[0];
    const float* cs  = (const float*)d_in[1];
    const float* fs  = (const float*)d_in[2];
    const float* W1  = (const float*)d_in[3];
    const float* b1  = (const float*)d_in[4];
    const float* W2  = (const float*)d_in[5];
    const float* b2  = (const float*)d_in[6];
    float* out = (float*)d_out;

    const int n = in_sizes[0];
    // 2048 blocks x 256 threads = 8 blocks/CU, exactly one residency round;
    // each thread handles 8 float4 (32 elements) via 4 grid-stride iterations.
    const int block = 256;
    const int grid  = 2048;

    ConsolidationDynamics_70068096467285_kernel<<<grid, block, 0, stream>>>(
        w, cs, fs, W1, b1, W2, b2, out, n);
}

// Round 3
// 124.415 us; speedup vs baseline: 1.0304x; 1.0039x over previous
//
#include <hip/hip_runtime.h>

#define CONS_RATE 0.001f
#define CLAMP_V   10.0f

// e^(2s) = 2^(s * 2/ln2)
#define TWO_LOG2E 2.88539008177792681472f

#if defined(__has_builtin)
#  if __has_builtin(__builtin_amdgcn_exp2f)
#    define EXP2F(x) __builtin_amdgcn_exp2f(x)
#  endif
#endif
#ifndef EXP2F
#  define EXP2F(x) __expf(0.69314718055994530942f * (x))
#endif

// Native clang vector type: __builtin_nontemporal_store requires this.
typedef float f32x4 __attribute__((ext_vector_type(4)));

// Per-element: out = clamp(w + 0.001*tanh(b2 + sum_j w2_j * relu(a_j*w + c_j)))
// a_j, v_j live in SGPRs; c_j pinned to VGPRs (1-SGPR-per-VALU-op limit).
//
// Round-3 change: register double-buffer streaming. The previous loop issued
// loads only at the top of each iteration, then ran ~600 VALU cycles with no
// memory op outstanding -> load-issue duty cycle ~15%, effective BW ~3.3 TB/s
// (half of achievable). Prefetching the next pair of float4s BEFORE computing
// the current pair keeps ~2KB/wave in flight through the whole compute phase.

__global__ __launch_bounds__(256) void ConsolidationDynamics_70068096467285_kernel(
    const float* __restrict__ w,
    const float* __restrict__ cs_p,
    const float* __restrict__ fs_p,
    const float* __restrict__ W1,   // (3,16) row-major
    const float* __restrict__ b1,   // (16,)
    const float* __restrict__ W2,   // (16,1)
    const float* __restrict__ b2,   // (1,)
    float* __restrict__ out,
    int n)
{
    const float cs = cs_p[0];
    const float fs = fs_p[0];
    float bb2 = b2[0];
    asm("" : "+v"(bb2));   // force VGPR residence

#define COEF(J) \
    const float a##J = W1[J]; \
    const float v##J = W2[J]; \
    float c##J = fmaf(cs, W1[16 + J], fmaf(fs, W1[32 + J], b1[J])); \
    asm("" : "+v"(c##J));
    COEF(0)  COEF(1)  COEF(2)  COEF(3)
    COEF(4)  COEF(5)  COEF(6)  COEF(7)
    COEF(8)  COEF(9)  COEF(10) COEF(11)
    COEF(12) COEF(13) COEF(14) COEF(15)
#undef COEF

#define TERM(J, sacc) { float h = fmaf(r_, a##J, c##J); h = fmaxf(h, 0.0f); \
                        sacc = fmaf(h, v##J, sacc); }

#define EVAL(rr, d) { \
    const float r_ = (rr); \
    float h0 = fmaf(r_, a0, c0); h0 = fmaxf(h0, 0.0f); float s0 = fmaf(h0, v0, bb2); \
    float h1 = fmaf(r_, a1, c1); h1 = fmaxf(h1, 0.0f); float s1 = h1 * v1; \
    TERM(2, s0)  TERM(3, s1)  TERM(4, s0)  TERM(5, s1)  \
    TERM(6, s0)  TERM(7, s1)  TERM(8, s0)  TERM(9, s1)  \
    TERM(10, s0) TERM(11, s1) TERM(12, s0) TERM(13, s1) \
    TERM(14, s0) TERM(15, s1) \
    const float e  = EXP2F((s0 + s1) * TWO_LOG2E); \
    const float u  = fmaf(-2.0f, __builtin_amdgcn_rcpf(e + 1.0f), 1.0f); \
    const float nw = fmaf(u, CONS_RATE, r_); \
    (d) = fminf(fmaxf(nw, -CLAMP_V), CLAMP_V); }

#define EVAL4(V, O) \
    EVAL((V).x, (O).x) EVAL((V).y, (O).y) EVAL((V).z, (O).z) EVAL((V).w, (O).w)

    const int n4 = n >> 2;
    const f32x4* __restrict__ w4 = (const f32x4*)w;
    f32x4* __restrict__ o4 = (f32x4*)out;

    const int nthreads = gridDim.x * blockDim.x;
    const int tid      = blockIdx.x * blockDim.x + threadIdx.x;
    const int step     = nthreads * 2;

    int i0 = tid;
    int i1 = tid + nthreads;

    if (i1 < n4) {
        // Prologue: load current pair.
        f32x4 A = w4[i0];
        f32x4 B = w4[i1];
        int j0 = i0 + step;
        int j1 = i1 + step;
        // Steady state: prefetch next pair, THEN compute current pair.
        // The 2 prefetch loads stay outstanding across the ~600-cycle
        // compute phase -> memory pipe never starves.
        while (j1 < n4) {
            const f32x4 A2 = w4[j0];
            const f32x4 B2 = w4[j1];
            f32x4 oA, oB;
            EVAL4(A, oA) EVAL4(B, oB)
            __builtin_nontemporal_store(oA, &o4[i0]);
            __builtin_nontemporal_store(oB, &o4[i1]);
            A = A2; B = B2;
            i0 = j0; i1 = j1;
            j0 += step; j1 += step;
        }
        // Epilogue: compute the last prefetched pair.
        f32x4 oA, oB;
        EVAL4(A, oA) EVAL4(B, oB)
        __builtin_nontemporal_store(oA, &o4[i0]);
        __builtin_nontemporal_store(oB, &o4[i1]);
        i0 += step;
        i1 += step;
    }
    // Remainder float4s (i0 may still be in range when i1 overshot).
    for (; i0 < n4; i0 += nthreads) {
        const f32x4 A = w4[i0];
        f32x4 oA;
        EVAL4(A, oA)
        __builtin_nontemporal_store(oA, &o4[i0]);
    }
    // Scalar tail (n % 4).
    for (int i = (n4 << 2) + tid; i < n; i += nthreads) {
        const float r = w[i];
        float d;
        EVAL(r, d)
        out[i] = d;
    }
#undef EVAL4
#undef EVAL
#undef TERM
}

extern "C" void kernel_launch(void* const* d_in, const int* in_sizes, int n_in,
                              void* d_out, int out_size, void* d_ws, size_t ws_size,
                              hipStream_t stream) {
    const float* w   = (const float*)d_in[0];
    const float* cs  = (const float*)d_in[1];
    const float* fs  = (const float*)d_in[2];
    const float* W1  = (const float*)d_in[3];
    const float* b1  = (const float*)d_in[4];
    const float* W2  = (const float*)d_in[5];
    const float* b2  = (const float*)d_in[6];
    float* out = (float*)d_out;

    const int n = in_sizes[0];
    // 2048 blocks x 256 threads = 8 blocks/CU, one residency round; each
    // thread streams 8 float4 (32 elements) through the prefetch pipeline.
    const int block = 256;
    const int grid  = 2048;

    ConsolidationDynamics_70068096467285_kernel<<<grid, block, 0, stream>>>(
        w, cs, fs, W1, b1, W2, b2, out, n);
}